// Round 19
// baseline (299.927 us; speedup 1.0000x reference)
//
#include <hip/hip_runtime.h>

// Problem constants (fixed by setup_inputs)
#define B_   4
#define C_   256
#define H_   96
#define W_   128
#define F_   9
#define G_   4
#define CG   64            // channels per group
#define NC8  8             // channel OCTETS per group
#define NO   81            // offsets
#define HW_  (H_ * W_)

// Padded NHWC f16 geometry for in2: rows -8..103, cols -8..135
#define PR_  112
#define PC_  144

// d_ws layout
#define WP_BYTES   ((size_t)G_ * NC8 * NO * 16)        // 41,472
#define IN2F_OFF   WP_BYTES
#define IN2F_BYTES ((size_t)16 * PR_ * PC_ * CG * 2)   // 33,030,144
#define WS_NEED    (IN2F_OFF + IN2F_BYTES)

typedef _Float16 half2v __attribute__((ext_vector_type(2)));
typedef unsigned u32x4 __attribute__((ext_vector_type(4)));

__device__ __forceinline__ half2v u2h(unsigned u) {
    half2v h; __builtin_memcpy(&h, &u, 4); return h;
}
__device__ __forceinline__ unsigned h2u(half2v h) {
    unsigned u; __builtin_memcpy(&u, &h, 4); return u;
}
__device__ __forceinline__ half2v pkrtz(float a, float b) {
    auto r = __builtin_amdgcn_cvt_pkrtz(a, b);
    half2v h; __builtin_memcpy(&h, &r, 4); return h;
}
__device__ __forceinline__ unsigned pkrtz_u(float a, float b) {
    auto r = __builtin_amdgcn_cvt_pkrtz(a, b);
    unsigned u; __builtin_memcpy(&u, &r, 4); return u;
}

#if __has_builtin(__builtin_amdgcn_fdot2)
#define FDOT2(a, b, c) __builtin_amdgcn_fdot2((a), (b), (c), false)
#else
__device__ __forceinline__ float fdot2_fb(half2v a, half2v b, float c) {
    return c + (float)a[0] * (float)b[0] + (float)a[1] * (float)b[1];
}
#define FDOT2(a, b, c) fdot2_fb((a), (b), (c))
#endif

// Pack weights [C,9,9] f32 -> [g][c8][o] as 8-channel (4x f16x2) in d_ws
__global__ void pack_weights_kernel(const float* __restrict__ w,
                                    u32x4* __restrict__ wp) {
    int i = blockIdx.x * blockDim.x + threadIdx.x;
    if (i >= G_ * NC8 * NO) return;
    int o  = i % NO;
    int c8 = (i / NO) % NC8;
    int g  = i / (NO * NC8);
    const float* base = w + (size_t)(g * CG + 8 * c8) * NO + o;
    u32x4 r;
    r.x = pkrtz_u(base[0 * NO], base[1 * NO]);
    r.y = pkrtz_u(base[2 * NO], base[3 * NO]);
    r.z = pkrtz_u(base[4 * NO], base[5 * NO]);
    r.w = pkrtz_u(base[6 * NO], base[7 * NO]);
    wp[i] = r;
}

// Repack in2 -> padded NHWC f16: [pair][prow 0..111][pcol 0..143][c 0..63]
// Block = (pair, prow). Coalesced reads -> LDS transpose -> coalesced writes.
__global__ __launch_bounds__(256)
void repack_in2_kernel(const float* __restrict__ in2,
                       unsigned short* __restrict__ in2f) {
    __shared__ unsigned short lds[PC_ * 66];   // [pcol][c], stride 66 halfs

    int blk  = blockIdx.x;          // 16 * 112
    int pair = blk / PR_;
    int prow = blk - pair * PR_;
    int b = pair >> 2, g = pair & 3;
    int gr = prow - 8;
    bool rok = (gr >= 0 && gr < H_);

    int t    = threadIdx.x;
    int lane = t & 63;
    int wv   = t >> 6;              // wave id 0..3

    if (rok) {
        // phase 1: coalesced f32 reads, LDS f16 writes (padded stride 66)
        const float* base = in2 + ((size_t)(b * C_ + g * CG) * H_ + gr) * W_;
#pragma unroll
        for (int cc = 0; cc < 16; ++cc) {
            int c = wv * 16 + cc;                    // wave-uniform channel
            const float* sp = base + (size_t)c * HW_;
            float v0 = sp[lane];
            float v1 = sp[64 + lane];
            lds[(8 + lane) * 66 + c]      = (unsigned short)(pkrtz_u(v0, v0) & 0xffffu);
            lds[(8 + 64 + lane) * 66 + c] = (unsigned short)(pkrtz_u(v1, v1) & 0xffffu);
        }
    }
    __syncthreads();

    // phase 2: coalesced 2B writes of the NHWC row (zeros in halo)
    unsigned short* dst = in2f + (size_t)(pair * PR_ + prow) * PC_ * CG;
    int c = t & 63;
#pragma unroll
    for (int k = 0; k < (PR_ + 32) / 4; ++k) {       // 36 iters cover 144 pcols
        int pcol = (t >> 6) + 4 * k;                 // wave-uniform
        unsigned short v = 0;
        if (rok && pcol >= 8 && pcol < 8 + W_)
            v = lds[pcol * 66 + c];
        dst[(size_t)pcol * CG + c] = v;
    }
}

// Main: no LDS, no barriers. 2 same-parity px/thread; taps direct from
// padded NHWC f16 (L1/L2). Window reuse: 10 tap loads serve 18 (px,dx).
__global__ __launch_bounds__(256)
void wcorr_direct(const float* __restrict__ in1,
                  const unsigned short* __restrict__ in2f,
                  const u32x4* __restrict__ wp,
                  float* __restrict__ out) {
    // grid = 1152 = 8 xcd x 144; pair constant per XCD chunk (L2 locality)
    int bid  = blockIdx.x;
    int xcd  = bid & 7;
    int slot = bid >> 3;                 // 0..143
    int pair = xcd + 8 * (slot / 72);    // 0..15
    int rem  = slot % 72;
    int pass = rem / 24;                 // 0..2
    int hblk = rem % 24;
    int b = pair >> 2, g = pair & 3;
    int h0 = hblk * 4;

    int t = threadIdx.x;
    int r = t >> 6;                      // 0..3 out row
    int i = t & 63;
    int j = i >> 1;                      // 0..31
    int p = i & 1;
    const int c0 = 4 * j + p;            // px0 col; px1 = c0 + 2
    const int h  = h0 + r;

    const float* in1g = in1 + (size_t)(b * C_ + g * CG) * HW_ + h * W_ + c0;
    const unsigned short* i2p = in2f + (size_t)pair * PR_ * PC_ * CG;

    float acc0[27], acc1[27];
#pragma unroll
    for (int o = 0; o < 27; ++o) { acc0[o] = 0.f; acc1[o] = 0.f; }

    for (int c8 = 0; c8 < NC8; ++c8) {
        const int co = c8 * 8;           // half offset within a 64-ch entry

        // in1 channel octet for both px, packed pair-wise (low live set)
        const float* ib = in1g + (size_t)co * HW_;
        half2v ha0 = pkrtz(ib[0], ib[HW_]);
        half2v hb0 = pkrtz(ib[2], ib[HW_ + 2]);
        half2v ha1 = pkrtz(ib[2 * HW_], ib[3 * HW_]);
        half2v hb1 = pkrtz(ib[2 * HW_ + 2], ib[3 * HW_ + 2]);
        half2v ha2 = pkrtz(ib[4 * HW_], ib[5 * HW_]);
        half2v hb2 = pkrtz(ib[4 * HW_ + 2], ib[5 * HW_ + 2]);
        half2v ha3 = pkrtz(ib[6 * HW_], ib[7 * HW_]);
        half2v hb3 = pkrtz(ib[6 * HW_ + 2], ib[7 * HW_ + 2]);

        const u32x4* wrow = wp + ((size_t)(g * NC8 + c8)) * NO + pass * 27;

#pragma unroll
        for (int dyp = 0; dyp < 3; ++dyp) {
            const int trow = h + 2 * (3 * pass + dyp);   // padded row, 0..111
            const unsigned short* rowp =
                i2p + ((size_t)trow * PC_ + c0) * CG + co;

            u32x4 wv = {0u, 0u, 0u, 0u}, wprev;
#pragma unroll
            for (int m = 0; m < 10; ++m) {
                // tap entry m: 16B aligned, imm offset m*256B
                u32x4 uv = *(const u32x4*)(rowp + (size_t)m * 2 * CG);
                wprev = wv;
                if (m <= 8) {
                    wv = wrow[dyp * 9 + m];          // uniform -> s_load
                    float s = acc0[dyp * 9 + m];
                    s = FDOT2(u2h(wv.x) * ha0, u2h(uv.x), s);
                    s = FDOT2(u2h(wv.y) * ha1, u2h(uv.y), s);
                    s = FDOT2(u2h(wv.z) * ha2, u2h(uv.z), s);
                    s = FDOT2(u2h(wv.w) * ha3, u2h(uv.w), s);
                    acc0[dyp * 9 + m] = s;
                }
                if (m >= 1) {
                    const int oo = dyp * 9 + m - 1;
                    float s = acc1[oo];
                    s = FDOT2(u2h(wprev.x) * hb0, u2h(uv.x), s);
                    s = FDOT2(u2h(wprev.y) * hb1, u2h(uv.y), s);
                    s = FDOT2(u2h(wprev.z) * hb2, u2h(uv.z), s);
                    s = FDOT2(u2h(wprev.w) * hb3, u2h(uv.w), s);
                    acc1[oo] = s;
                }
            }
        }
    }

    // out[b][g*81 + pass*27 + oo][h][c0], [c0+2]
    size_t obase = (((size_t)(pair * NO + pass * 27)) * H_ + h) * W_ + c0;
#pragma unroll
    for (int oo = 0; oo < 27; ++oo) {
        out[obase + (size_t)oo * HW_]     = acc0[oo];
        out[obase + (size_t)oo * HW_ + 2] = acc1[oo];
    }
}

// ---------------- R11 fallback (proven 74.6 us) if ws too small -------------
#define NDY   3
#define TROWS 8
#define TCOLS 80
#define PTE   (TROWS * TCOLS)
#define PNK   3

template <bool PACKED>
__global__ __launch_bounds__(256)
void wcorr_kernel(const float* __restrict__ in1, const float* __restrict__ in2,
                  const u32x4* __restrict__ wp, const float* __restrict__ wraw,
                  float* __restrict__ out) {
    __shared__ u32x4 tile[2][PTE];

    int bid  = blockIdx.x;
    int xcd  = bid & 7;
    int slot = bid >> 3;
    int pair = xcd + 8 * (slot / 144);
    int rem  = slot % 144;
    int pass = rem / 48;
    int sub  = rem % 48;
    int hblk = sub >> 1;
    int half = sub & 1;
    int b = pair >> 2, g = pair & 3;
    int h0 = hblk * 4;
    int w0 = half * 64;

    int t = threadIdx.x;
    int r = t >> 6;
    int x = t & 63;

    const float* in1g = in1 + (size_t)(b * C_ + g * CG) * HW_;
    const float* in2g = in2 + (size_t)(b * C_ + g * CG) * HW_;

    const int gr0 = h0 - 8 + 6 * pass;
    const int gc0 = w0 - 8;
    int po[PNK]; unsigned msk[PNK];
#pragma unroll
    for (int k = 0; k < PNK; ++k) {
        int pidx = k * 256 + t;
        int row  = pidx / TCOLS;
        int col  = pidx - row * TCOLS;
        int gr = gr0 + row, gc = gc0 + col;
        bool inb = (pidx < PTE) && gr >= 0 && gr < H_ && gc >= 0 && gc < W_;
        int off = gr * W_ + gc;
        off = off < 0 ? 0 : (off > HW_ - 1 ? HW_ - 1 : off);
        po[k]  = off;
        float m = inb ? 1.f : 0.f;
        msk[k] = pkrtz_u(m, m);
    }

    float acc[NDY * F_];
#pragma unroll
    for (int o = 0; o < NDY * F_; ++o) acc[o] = 0.f;

    float sv[PNK][8];

    auto LOADS = [&](int c8n) {
        const float* chb = in2g + (size_t)(8 * c8n) * HW_;
#pragma unroll
        for (int k = 0; k < PNK; ++k) {
            const float* q = chb + po[k];
#pragma unroll
            for (int jj = 0; jj < 8; ++jj) sv[k][jj] = q[(size_t)jj * HW_];
        }
    };
    auto WRITE = [&](u32x4* dst) {
#pragma unroll
        for (int k = 0; k < PNK; ++k) {
            if (k < PNK - 1 || t < PTE - (PNK - 1) * 256) {
                half2v m = u2h(msk[k]);
                u32x4 e;
                e.x = h2u(u2h(pkrtz_u(sv[k][0], sv[k][1])) * m);
                e.y = h2u(u2h(pkrtz_u(sv[k][2], sv[k][3])) * m);
                e.z = h2u(u2h(pkrtz_u(sv[k][4], sv[k][5])) * m);
                e.w = h2u(u2h(pkrtz_u(sv[k][6], sv[k][7])) * m);
                dst[k * 256 + t] = e;
            }
        }
    };

    LOADS(0);
    WRITE(tile[0]);
    LOADS(1);

    const int in1off = (h0 + r) * W_ + (w0 + x);
    float a[8];
#pragma unroll
    for (int jj = 0; jj < 8; ++jj) a[jj] = in1g[in1off + (size_t)jj * HW_];

    for (int c8 = 0; c8 < NC8; ++c8) {
        __syncthreads();
        if (c8 + 1 < NC8) WRITE(tile[(c8 + 1) & 1]);
        if (c8 + 2 < NC8) LOADS(c8 + 2);

        half2v ha0 = pkrtz(a[0], a[1]), ha1 = pkrtz(a[2], a[3]);
        half2v ha2 = pkrtz(a[4], a[5]), ha3 = pkrtz(a[6], a[7]);
        if (c8 + 1 < NC8) {
            const float* pp = in1g + (size_t)(8 * (c8 + 1)) * HW_ + in1off;
#pragma unroll
            for (int jj = 0; jj < 8; ++jj) a[jj] = pp[(size_t)jj * HW_];
        }

        const u32x4* lt = tile[c8 & 1];
        const u32x4* wrow = PACKED ? (wp + ((size_t)g * NC8 + c8) * NO + pass * NDY * F_) : nullptr;
        const float* wr = wraw + (size_t)(g * CG + 8 * c8) * NO + pass * NDY * F_;

#pragma unroll
        for (int dyp = 0; dyp < NDY; ++dyp) {
            const u32x4* rowp = lt + (r + 2 * dyp) * TCOLS + x;
#pragma unroll
            for (int dx = 0; dx < F_; ++dx) {
                const int oo = dyp * F_ + dx;
                u32x4 uv = rowp[2 * dx];
                half2v w0h, w1h, w2h, w3h;
                if (PACKED) {
                    u32x4 wv = wrow[oo];
                    w0h = u2h(wv.x); w1h = u2h(wv.y);
                    w2h = u2h(wv.z); w3h = u2h(wv.w);
                } else {
                    w0h = pkrtz(wr[oo + 0 * NO], wr[oo + 1 * NO]);
                    w1h = pkrtz(wr[oo + 2 * NO], wr[oo + 3 * NO]);
                    w2h = pkrtz(wr[oo + 4 * NO], wr[oo + 5 * NO]);
                    w3h = pkrtz(wr[oo + 6 * NO], wr[oo + 7 * NO]);
                }
                float s = acc[oo];
                s = FDOT2(w0h * ha0, u2h(uv.x), s);
                s = FDOT2(w1h * ha1, u2h(uv.y), s);
                s = FDOT2(w2h * ha2, u2h(uv.z), s);
                s = FDOT2(w3h * ha3, u2h(uv.w), s);
                acc[oo] = s;
            }
        }
    }

    size_t obase = (((size_t)pair * NO + pass * NDY * F_) * H_ + (h0 + r)) * W_ + (w0 + x);
#pragma unroll
    for (int oo = 0; oo < NDY * F_; ++oo)
        out[obase + (size_t)oo * HW_] = acc[oo];
}

extern "C" void kernel_launch(void* const* d_in, const int* in_sizes, int n_in,
                              void* d_out, int out_size, void* d_ws, size_t ws_size,
                              hipStream_t stream) {
    const float* in1  = (const float*)d_in[0];
    const float* in2  = (const float*)d_in[1];
    const float* wraw = (const float*)d_in[2];
    float* out = (float*)d_out;

    if (ws_size >= WS_NEED) {
        u32x4* wpq = (u32x4*)d_ws;
        unsigned short* in2f = (unsigned short*)((char*)d_ws + IN2F_OFF);
        int n = G_ * NC8 * NO;
        pack_weights_kernel<<<(n + 255) / 256, 256, 0, stream>>>(wraw, wpq);
        repack_in2_kernel<<<16 * PR_, 256, 0, stream>>>(in2, in2f);
        wcorr_direct<<<1152, 256, 0, stream>>>(in1, in2f, wpq, out);
    } else if (ws_size >= WP_BYTES) {
        u32x4* wpq = (u32x4*)d_ws;
        int n = G_ * NC8 * NO;
        pack_weights_kernel<<<(n + 255) / 256, 256, 0, stream>>>(wraw, wpq);
        wcorr_kernel<true><<<2304, 256, 0, stream>>>(in1, in2, wpq, wraw, out);
    } else {
        wcorr_kernel<false><<<2304, 256, 0, stream>>>(in1, in2, nullptr, wraw, out);
    }
}